// Round 5
// baseline (273.365 us; speedup 1.0000x reference)
//
#include <hip/hip_runtime.h>
#include <math.h>

#define NN 50000
#define NE 500000
#define NF 128
#define NO 16
#define SCAN_B 1024
#define NB_SCAN 49   // (NN+SCAN_B-1)/SCAN_B
#define NPART 16
#define EB4 489      // blocks of 1024 edges (4/thread)
#define EB2 977      // blocks of 512 edges (2/thread)

static_assert(NN < 65536, "src must fit u16");

typedef _Float16 f16x8 __attribute__((ext_vector_type(8)));
typedef _Float16 f16x4 __attribute__((ext_vector_type(4)));
typedef float f32x4 __attribute__((ext_vector_type(4)));

union HU { unsigned short u; _Float16 h; };

__device__ inline float rec_w(unsigned int rec) {
    HU cu; cu.u = (unsigned short)(rec >> 16);
    return (float)cu.h;
}

// ---------------- graph preprocessing (atomic-light CSR build) ----------------
// Edge partition for rank disambiguation: part(e) = (e >> 10) & 15.

// pass 1: per-edge rank within (partition, dst) via returning atomics, 4 edges
// per thread for memory-level parallelism; spare blocks transpose W1/W2 to fp16.
__global__ __launch_bounds__(256) void k_count_rank(const int* __restrict__ dst,
                                                    int* __restrict__ pcnt,
                                                    int* __restrict__ rank, int E,
                                                    const float* __restrict__ W1,
                                                    const float* __restrict__ W2,
                                                    _Float16* __restrict__ W1T,
                                                    _Float16* __restrict__ W2T) {
    int b = blockIdx.x;
    if (b < EB4 - 1) {
        int part = b & (NPART - 1);
        int e0 = b * 1024 + threadIdx.x;
        int d0 = dst[e0], d1 = dst[e0 + 256], d2 = dst[e0 + 512], d3 = dst[e0 + 768];
        int r0 = atomicAdd(&pcnt[part * NN + d0], 1);
        int r1 = atomicAdd(&pcnt[part * NN + d1], 1);
        int r2 = atomicAdd(&pcnt[part * NN + d2], 1);
        int r3 = atomicAdd(&pcnt[part * NN + d3], 1);
        rank[e0]       = r0;
        rank[e0 + 256] = r1;
        rank[e0 + 512] = r2;
        rank[e0 + 768] = r3;
    } else if (b == EB4 - 1) {
        int part = b & (NPART - 1);
#pragma unroll
        for (int k = 0; k < 4; ++k) {
            int e = b * 1024 + k * 256 + threadIdx.x;
            if (e < E) {
                int d = dst[e];
                rank[e] = atomicAdd(&pcnt[part * NN + d], 1);
            }
        }
    } else {
        int idx = (b - EB4) * 256 + threadIdx.x;   // [0,16384)
        int r = idx >> 7, c = idx & 127;
        W1T[(size_t)c * NF + r] = (_Float16)W1[idx];
        W2T[(size_t)c * NF + r] = (_Float16)W2[idx];
    }
}

// pass 2: per-node partition bases (in place) + block scan of totals + fused
// 49-block top-level scan via last-block pattern (agent-scope atomics).
__global__ void k_scan1f(int* __restrict__ pcnt, int* __restrict__ offs_p,
                         int* __restrict__ bsums, int* __restrict__ done) {
    __shared__ int sm[SCAN_B];
    __shared__ int isLast;
    int t = threadIdx.x;
    int i = blockIdx.x * SCAN_B + t;
    int c = 0;
    if (i < NN) {
        int run = 0;
#pragma unroll
        for (int p = 0; p < NPART; ++p) {
            int v = pcnt[p * NN + i];
            pcnt[p * NN + i] = run;
            run += v;
        }
        c = run;
    }
    sm[t] = c;
    __syncthreads();
    for (int off = 1; off < SCAN_B; off <<= 1) {
        int x = (t >= off) ? sm[t - off] : 0;
        __syncthreads();
        sm[t] += x;
        __syncthreads();
    }
    if (i < NN) offs_p[i] = sm[t] - c;
    if (t == SCAN_B - 1) {
        __hip_atomic_store(&bsums[blockIdx.x], sm[t], __ATOMIC_RELEASE,
                           __HIP_MEMORY_SCOPE_AGENT);
        int old = __hip_atomic_fetch_add(done, 1, __ATOMIC_ACQ_REL,
                                         __HIP_MEMORY_SCOPE_AGENT);
        isLast = (old == (int)gridDim.x - 1) ? 1 : 0;
    }
    __syncthreads();
    if (isLast && t < 64) {
        int v = (t < NB_SCAN) ? __hip_atomic_load(&bsums[t], __ATOMIC_ACQUIRE,
                                                  __HIP_MEMORY_SCOPE_AGENT) : 0;
        int orig = v;
#pragma unroll
        for (int off = 1; off < 64; off <<= 1) {
            int u = __shfl_up(v, off, 64);
            if (t >= off) v += u;
        }
        if (t < NB_SCAN)
            __hip_atomic_store(&bsums[t], v - orig, __ATOMIC_RELEASE,
                               __HIP_MEMORY_SCOPE_AGENT);
    }
}

// pass 3: atomic-free scatter of packed 4B {src:u16, ew:fp16} records, 2/thread.
// ALSO accumulates weighted in-degree (fire-and-forget float atomics) so the
// separate dinv pass disappears; consumers compute rsqrt(1+deg) inline.
__global__ __launch_bounds__(256) void k_scatter(const int* __restrict__ src,
                                                 const int* __restrict__ dst,
                                                 const float* __restrict__ ew,
                                                 const int* __restrict__ pcnt,
                                                 const int* __restrict__ rank,
                                                 const int* __restrict__ offs_p,
                                                 const int* __restrict__ bsums,
                                                 unsigned int* __restrict__ erec,
                                                 float* __restrict__ deg, int E) {
    int b = blockIdx.x;
#pragma unroll
    for (int k = 0; k < 2; ++k) {
        int e = b * 512 + k * 256 + threadIdx.x;
        if (e < E) {
            int part = (e >> 10) & (NPART - 1);
            int d = dst[e];
            float w = ew[e];
            int pos = offs_p[d] + bsums[d >> 10] + pcnt[part * NN + d] + rank[e];
            HU cu; cu.h = (_Float16)w;
            erec[pos] = (unsigned int)src[e] | ((unsigned int)cu.u << 16);
            atomicAdd(&deg[d], w);
        }
    }
}

// ---------------- MFMA GEMM: Z[M,128](fp16, row-major) = dinv ⊙ (X @ W) ----------------

__device__ inline f16x8 afrag_load(const float* X, int row, int k0) {
    const float4* p = (const float4*)(X + (size_t)row * NF + k0);
    float4 a = p[0], b = p[1];
    f16x8 r;
    r[0] = (_Float16)a.x; r[1] = (_Float16)a.y; r[2] = (_Float16)a.z; r[3] = (_Float16)a.w;
    r[4] = (_Float16)b.x; r[5] = (_Float16)b.y; r[6] = (_Float16)b.z; r[7] = (_Float16)b.w;
    return r;
}
__device__ inline f16x8 afrag_load(const _Float16* X, int row, int k0) {
    return *(const f16x8*)(X + (size_t)row * NF + k0);
}

template <typename TA>
__global__ __launch_bounds__(256) void k_gemm_mfma(const TA* __restrict__ X,
                                                   const _Float16* __restrict__ WT,
                                                   const float* __restrict__ deg,
                                                   _Float16* __restrict__ Z, int M) {
    __shared__ _Float16 ls[4][16 * 136];      // padded stride 136 halves
    const int tid  = threadIdx.x;
    const int w    = tid >> 6;
    const int lane = tid & 63;
    const int n16  = lane & 15;
    const int quad = lane >> 4;
    const int r0   = blockIdx.x * 64 + w * 16;

    int arow = r0 + n16; if (arow > M - 1) arow = M - 1;

    f32x4 acc[8];
#pragma unroll
    for (int c = 0; c < 8; ++c) acc[c] = (f32x4){0.f, 0.f, 0.f, 0.f};

#pragma unroll
    for (int kk = 0; kk < 4; ++kk) {
        int k0 = kk * 32 + quad * 8;
        f16x8 a = afrag_load(X, arow, k0);
#pragma unroll
        for (int c = 0; c < 8; ++c) {
            f16x8 b = *(const f16x8*)(WT + (size_t)(c * 16 + n16) * NF + k0);
            acc[c] = __builtin_amdgcn_mfma_f32_16x16x32_f16(a, b, acc[c], 0, 0, 0);
        }
    }

#pragma unroll
    for (int reg = 0; reg < 4; ++reg) {
        int lrow = quad * 4 + reg;
        int grow = r0 + lrow; if (grow > M - 1) grow = M - 1;
        float di = rsqrtf(1.0f + deg[grow]);
#pragma unroll
        for (int c = 0; c < 8; ++c)
            ls[w][lrow * 136 + c * 16 + n16] = (_Float16)(acc[c][reg] * di);
    }
    __syncthreads();
#pragma unroll
    for (int i = 0; i < 4; ++i) {
        int off16 = i * 64 + lane;
        int row = off16 >> 4;
        int col = off16 & 15;
        int grow = r0 + row;
        if (grow < M) {
            f16x8 v = *(const f16x8*)(&ls[w][row * 136 + col * 8]);
            *(f16x8*)(Z + (size_t)grow * NF + col * 8) = v;
        }
    }
}

// ---------------- shared gather body (round-2 masked uniform loop) ----------------
// acc[0..3] += sum_e w_e * z[src_e][li*4..+4]; includes cross-half reduction.
__device__ __forceinline__ void agg_gather(const _Float16* __restrict__ z,
                                           const int* __restrict__ offs_p,
                                           const int* __restrict__ bsums,
                                           const unsigned int* __restrict__ erec,
                                           int n, int lane, int half, int li,
                                           float& acc0, float& acc1,
                                           float& acc2, float& acc3) {
    int s = offs_p[n] + bsums[n >> 10];
    int e = (n + 1 < NN) ? offs_p[n + 1] + bsums[(n + 1) >> 10] : NE;
    for (int base = s; base < e; base += 64) {
        int cnt = e - base; if (cnt > 64) cnt = 64;
        unsigned int rec = 0u;
        if (lane < cnt) rec = __builtin_nontemporal_load(erec + base + lane);
        int   my_s = rec & 0xFFFF;
        float my_w = rec_w(rec);
        int cm1 = cnt - 1;
        for (int k = 0; k < cnt; k += 16) {
            int   sv[8];
            float wv[8];
            f16x4 v[8];
#pragma unroll
            for (int t = 0; t < 8; ++t) {
                int ei = k + 2 * t + half;
                int ec = ei < cm1 ? ei : cm1;
                sv[t] = __shfl(my_s, ec, 64);
                float wt = __shfl(my_w, ec, 64);
                wv[t] = (ei < cnt) ? wt : 0.0f;
            }
#pragma unroll
            for (int t = 0; t < 8; ++t)
                v[t] = *(const f16x4*)(z + ((size_t)sv[t] << 7) + li * 4);
#pragma unroll
            for (int t = 0; t < 8; ++t) {
                acc0 = fmaf((float)v[t][0], wv[t], acc0);
                acc1 = fmaf((float)v[t][1], wv[t], acc1);
                acc2 = fmaf((float)v[t][2], wv[t], acc2);
                acc3 = fmaf((float)v[t][3], wv[t], acc3);
            }
        }
    }
    acc0 += __shfl_xor(acc0, 32, 64);
    acc1 += __shfl_xor(acc1, 32, 64);
    acc2 += __shfl_xor(acc2, 32, 64);
    acc3 += __shfl_xor(acc3, 32, 64);
}

// ---------------- aggregation, 128-wide (layer 1: writes h) ----------------
__global__ __launch_bounds__(256) void k_agg128h(const _Float16* __restrict__ z,
                                                 const float* __restrict__ deg,
                                                 const int* __restrict__ offs_p,
                                                 const int* __restrict__ bsums,
                                                 const unsigned int* __restrict__ erec,
                                                 const float* __restrict__ bias,
                                                 _Float16* __restrict__ hout) {
    const int tid  = threadIdx.x;
    const int lane = tid & 63;
    const int half = lane >> 5;      // edge parity
    const int li   = lane & 31;      // feature chunk [li*4, li*4+4)
    int n = __builtin_amdgcn_readfirstlane(blockIdx.x * 4 + (tid >> 6));

    float acc0 = 0.f, acc1 = 0.f, acc2 = 0.f, acc3 = 0.f;
    agg_gather(z, offs_p, bsums, erec, n, lane, half, li, acc0, acc1, acc2, acc3);

    f16x4 sv = *(const f16x4*)(z + ((size_t)n << 7) + li * 4);
    float di = rsqrtf(1.0f + deg[n]);
    float4 bb = *(const float4*)(bias + li * 4);
    float r0 = fmaxf(fmaf(di, (float)sv[0] + acc0, bb.x), 0.0f);
    float r1 = fmaxf(fmaf(di, (float)sv[1] + acc1, bb.y), 0.0f);
    float r2 = fmaxf(fmaf(di, (float)sv[2] + acc2, bb.z), 0.0f);
    float r3 = fmaxf(fmaf(di, (float)sv[3] + acc3, bb.w), 0.0f);
    if (half == 0) {
        f16x4 o;
        o[0] = (_Float16)r0; o[1] = (_Float16)r1;
        o[2] = (_Float16)r2; o[3] = (_Float16)r3;
        __builtin_nontemporal_store(o, (f16x4*)(hout + ((size_t)n << 7) + li * 4));
    }
}

// ---------------- layer-2 aggregation FUSED with 128->16 matvec ----------------
// h2 row lives in registers; z3[n][c] = dinv*sum_k relu(h2)[k]*W3[k][c].
// W3 in LDS TRANSPOSED+SWIZZLED: w3t[c*132 + k + (k>>5)] so the matvec read
// bank = (4c+q+4m) mod 32 with 4c+q a bijection onto [0,64) -> 2-way max (free).
// (Round-1's w3s[k*16+c] was an 8-way structural conflict: 3.2M SQ_LDS_BANK_CONFLICT.)
__global__ __launch_bounds__(256) void k_agg128f(const _Float16* __restrict__ z,
                                                 const float* __restrict__ deg,
                                                 const int* __restrict__ offs_p,
                                                 const int* __restrict__ bsums,
                                                 const unsigned int* __restrict__ erec,
                                                 const float* __restrict__ bias,
                                                 const float* __restrict__ W3,
                                                 _Float16* __restrict__ z3) {
    __shared__ float w3t[NO * 132];
    const int tid  = threadIdx.x;
    for (int i = tid; i < NF * NO; i += 256) {
        int k = i >> 4, c = i & 15;
        w3t[c * 132 + k + (k >> 5)] = W3[i];
    }
    const int lane = tid & 63;
    const int half = lane >> 5;
    const int li   = lane & 31;
    int n = __builtin_amdgcn_readfirstlane(blockIdx.x * 4 + (tid >> 6));
    __syncthreads();   // w3t ready

    float acc0 = 0.f, acc1 = 0.f, acc2 = 0.f, acc3 = 0.f;
    agg_gather(z, offs_p, bsums, erec, n, lane, half, li, acc0, acc1, acc2, acc3);

    f16x4 sv = *(const f16x4*)(z + ((size_t)n << 7) + li * 4);
    float di = rsqrtf(1.0f + deg[n]);
    float4 bb = *(const float4*)(bias + li * 4);
    float r0 = fmaxf(fmaf(di, (float)sv[0] + acc0, bb.x), 0.0f);
    float r1 = fmaxf(fmaf(di, (float)sv[1] + acc1, bb.y), 0.0f);
    float r2 = fmaxf(fmaf(di, (float)sv[2] + acc2, bb.z), 0.0f);
    float r3 = fmaxf(fmaf(di, (float)sv[3] + acc3, bb.w), 0.0f);

    // matvec: lane (q=lane>>4, c=lane&15) accumulates k in [q*32, q*32+32)
    const int c = lane & 15, q = lane >> 4;
    float p = 0.f;
#pragma unroll
    for (int m = 0; m < 8; ++m) {
        int sl = q * 8 + m;                // source lane holding h[k], k=sl*4+j
        float h0 = __shfl(r0, sl, 64), h1 = __shfl(r1, sl, 64);
        float h2 = __shfl(r2, sl, 64), h3 = __shfl(r3, sl, 64);
        int kb = c * 132 + q * 33 + m * 4;     // swizzled: k + (k>>5) = q*33+m*4+j
        p = fmaf(h0, w3t[kb],     p);
        p = fmaf(h1, w3t[kb + 1], p);
        p = fmaf(h2, w3t[kb + 2], p);
        p = fmaf(h3, w3t[kb + 3], p);
    }
    p += __shfl_xor(p, 16, 64);
    p += __shfl_xor(p, 32, 64);
    if (lane < 16) z3[((size_t)n << 4) + lane] = (_Float16)(p * di);
}

// ---------------- final aggregation (16-wide) + bias + log_softmax ----------------
// 16-edge prefetch batch -> chain depth 2 instead of deg/2 serial round-trips.
__global__ __launch_bounds__(256) void k_agg16_ls(const _Float16* __restrict__ z3,
                                                  const float* __restrict__ deg,
                                                  const int* __restrict__ offs_p,
                                                  const int* __restrict__ bsums,
                                                  const unsigned int* __restrict__ erec,
                                                  const float* __restrict__ bias,
                                                  float* __restrict__ out) {
    int tid = threadIdx.x;
    int ln = tid >> 4, c = tid & 15;
    int n = blockIdx.x * 16 + ln;
    float acc = (float)z3[((size_t)n << 4) + c];
    int s = offs_p[n] + bsums[n >> 10];
    int e = (n + 1 < NN) ? offs_p[n + 1] + bsums[(n + 1) >> 10] : NE;
    for (int k = s; k < e; k += 16) {
        float vv[16], ww[16];
#pragma unroll
        for (int t = 0; t < 16; ++t) {
            int idx = k + t;
            int ic = idx < e ? idx : e - 1;
            unsigned int r = erec[ic];
            vv[t] = (float)z3[((size_t)(r & 0xFFFF) << 4) + c];
            ww[t] = (idx < e) ? rec_w(r) : 0.0f;
        }
#pragma unroll
        for (int t = 0; t < 16; ++t) acc = fmaf(vv[t], ww[t], acc);
    }
    float di = rsqrtf(1.0f + deg[n]);
    acc = fmaf(di, acc, bias[c]);
    float m = acc;
#pragma unroll
    for (int off = 8; off > 0; off >>= 1) m = fmaxf(m, __shfl_xor(m, off, 16));
    float ex = expf(acc - m);
    float ss = ex;
#pragma unroll
    for (int off = 8; off > 0; off >>= 1) ss += __shfl_xor(ss, off, 16);
    out[(size_t)n * NO + c] = acc - m - logf(ss);
}

// ---------------- launch ----------------

extern "C" void kernel_launch(void* const* d_in, const int* in_sizes, int n_in,
                              void* d_out, int out_size, void* d_ws, size_t ws_size,
                              hipStream_t stream) {
    const float* x   = (const float*)d_in[0];
    const int*   esrc= (const int*)  d_in[1];
    const int*   edst= (const int*)  d_in[2];
    const float* ew  = (const float*)d_in[3];
    const float* W1  = (const float*)d_in[4];
    const float* b1  = (const float*)d_in[5];
    const float* W2  = (const float*)d_in[6];
    const float* b2  = (const float*)d_in[7];
    const float* W3  = (const float*)d_in[8];
    const float* b3  = (const float*)d_in[9];
    float* out = (float*)d_out;

    // workspace carve
    char* p = (char*)d_ws;
    _Float16* z   = (_Float16*)p; p += (size_t)NN * NF * 2;   // 12.8 MB
    _Float16* h   = (_Float16*)p; p += (size_t)NN * NF * 2;   // 12.8 MB (layer-1 only)
    _Float16* z3  = (_Float16*)p; p += (size_t)NN * NO * 2;   // 1.6 MB
    unsigned int* erec = (unsigned int*)p; p += (size_t)NE * 4;
    int*   rank   = (int*)p;   p += (size_t)NE * 4;
    // zeroed region: pcnt | deg | done (single memset)
    int*   pcnt   = (int*)p;   p += (size_t)NPART * NN * 4;   // 3.2 MB
    float* deg    = (float*)p; p += (size_t)NN * 4;           // 0.2 MB
    int*   done   = (int*)p;   p += 64;
    int*   offs_p = (int*)p;   p += (size_t)(NN + 1) * 4;
    int*   bsums  = (int*)p;   p += 256;
    _Float16* W1T = (_Float16*)p; p += (size_t)NF * NF * 2;
    _Float16* W2T = (_Float16*)p; p += (size_t)NF * NF * 2;

    hipMemsetAsync(pcnt, 0, (size_t)NPART * NN * 4 + (size_t)NN * 4 + 64, stream);

    k_count_rank<<<EB4 + 64, 256, 0, stream>>>(edst, pcnt, rank, NE, W1, W2, W1T, W2T);
    k_scan1f<<<NB_SCAN, SCAN_B, 0, stream>>>(pcnt, offs_p, bsums, done);
    k_scatter<<<EB2, 256, 0, stream>>>(esrc, edst, ew, pcnt, rank, offs_p, bsums, erec, deg, NE);

    // layer 1
    k_gemm_mfma<float><<<(NN + 63) / 64, 256, 0, stream>>>(x, W1T, deg, z, NN);
    k_agg128h<<<NN / 4, 256, 0, stream>>>(z, deg, offs_p, bsums, erec, b1, h);
    // layer 2 (+fused 128->16 matvec; h2 never hits memory)
    k_gemm_mfma<_Float16><<<(NN + 63) / 64, 256, 0, stream>>>(h, W2T, deg, z, NN);
    k_agg128f<<<NN / 4, 256, 0, stream>>>(z, deg, offs_p, bsums, erec, b2, W3, z3);
    // layer 3 aggregation + log_softmax
    k_agg16_ls<<<NN / 16, 256, 0, stream>>>(z3, deg, offs_p, bsums, erec, b3, out);
}